// Round 2
// baseline (576.843 us; speedup 1.0000x reference)
//
#include <hip/hip_runtime.h>
#include <hip/hip_bf16.h>

#define NN 50000
#define NE 400000

typedef __bf16 bf16_t;
typedef __bf16 bf16x8 __attribute__((ext_vector_type(8)));
typedef float  floatx4 __attribute__((ext_vector_type(4)));

static __device__ __forceinline__ floatx4 mfma16(bf16x8 a, bf16x8 b, floatx4 c) {
    return __builtin_amdgcn_mfma_f32_16x16x32_bf16(a, b, c, 0, 0, 0);
}

static __device__ __forceinline__ float sigm_f(float x) {
    return 1.f / (1.f + __expf(-x));
}
static __device__ __forceinline__ float tanh_f(float x) {
    return 1.f - 2.f / (__expf(2.f * x) + 1.f);
}

// ---------------------------------------------------------------------------
// prep: transpose fp32 weights -> bf16 W1t[128][160] (k-padded), W2t[64][128].
// 28672 threads total.
// ---------------------------------------------------------------------------
__global__ __launch_bounds__(256) void prep_kernel(
    const float* __restrict__ Wm1, const float* __restrict__ Wm2,
    bf16_t* __restrict__ W1t, bf16_t* __restrict__ W2t)
{
    int u = blockIdx.x * 256 + threadIdx.x;
    if (u < 20480) {            // W1t[n*160+k] = (k<136) ? Wm1[k*128+n] : 0
        int n = u / 160, k = u - n * 160;
        W1t[u] = (k < 136) ? (bf16_t)Wm1[k * 128 + n] : (bf16_t)0.f;
        return;
    }
    u -= 20480;
    if (u < 8192) {             // W2t[n*128+k] = Wm2[k*64+n]
        int n = u / 128, k = u - n * 128;
        W2t[u] = (bf16_t)Wm2[k * 64 + n];
    }
}

// ---------------------------------------------------------------------------
// edge kernel: 64 edges/block, MFMA 16x16x32 bf16, fp32 accumulate.
// Gathers fp32 h rows + fp32 edge feats, converts to bf16 in LDS.
// GEMM1: [64 x 160] x [160 x 128] -> relu -> Hid (bf16 LDS)
// GEMM2: [64 x 128] x [128 x 64]  -> + b2 -> atomicAdd scatter to agg (fp32)
// ---------------------------------------------------------------------------
__global__ __launch_bounds__(256) void edge_kernel(
    const float* __restrict__ h, const float* __restrict__ ef,
    const int* __restrict__ esrc, const int* __restrict__ edst,
    const bf16_t* __restrict__ W1t, const bf16_t* __restrict__ W2t,
    const float* __restrict__ b1f, const float* __restrict__ b2f,
    float* __restrict__ agg)
{
    __shared__ __attribute__((aligned(16))) bf16_t xs[64 * 168];  // pitch 336 B
    __shared__ __attribute__((aligned(16))) bf16_t hs[64 * 136];  // pitch 272 B
    __shared__ int sidx[64];
    __shared__ int didx[64];

    const int tid = threadIdx.x;
    const int e0  = blockIdx.x * 64;

    if (tid < 64) { sidx[tid] = esrc[e0 + tid]; didx[tid] = edst[e0 + tid]; }
    __syncthreads();

    // stage X tile: 64 rows x 21 chunks of 8 bf16 (src 8, dst 8, ef 1, pad 4)
    for (int c = tid; c < 64 * 21; c += 256) {
        int r = c / 21, p = c - r * 21;
        bf16x8 v;
        if (p < 17) {
            const float* sp;
            if (p < 8)       sp = h  + (size_t)sidx[r] * 64 + p * 8;
            else if (p < 16) sp = h  + (size_t)didx[r] * 64 + (p - 8) * 8;
            else             sp = ef + (size_t)(e0 + r) * 8;
            float4 f0 = *(const float4*)sp;
            float4 f1 = *(const float4*)(sp + 4);
            v[0] = (bf16_t)f0.x; v[1] = (bf16_t)f0.y;
            v[2] = (bf16_t)f0.z; v[3] = (bf16_t)f0.w;
            v[4] = (bf16_t)f1.x; v[5] = (bf16_t)f1.y;
            v[6] = (bf16_t)f1.z; v[7] = (bf16_t)f1.w;
        } else {
            #pragma unroll
            for (int q = 0; q < 8; q++) v[q] = (bf16_t)0.f;
        }
        *(bf16x8*)(xs + r * 168 + p * 8) = v;
    }
    __syncthreads();

    const int lane = tid & 63;
    const int wv   = tid >> 6;       // wave -> edge rows [wv*16, wv*16+16)
    const int l15  = lane & 15;
    const int quad = lane >> 4;

    // ---- GEMM1 ----
    bf16x8 af[5];
    {
        const bf16_t* ap = xs + (wv * 16 + l15) * 168 + quad * 8;
        #pragma unroll
        for (int ks = 0; ks < 5; ks++) af[ks] = *(const bf16x8*)(ap + ks * 32);
    }
    floatx4 acc[8];
    #pragma unroll
    for (int nt = 0; nt < 8; nt++) { acc[nt].x = 0.f; acc[nt].y = 0.f; acc[nt].z = 0.f; acc[nt].w = 0.f; }
    #pragma unroll
    for (int nt = 0; nt < 8; nt++) {
        const bf16_t* bp = W1t + (nt * 16 + l15) * 160 + quad * 8;
        #pragma unroll
        for (int ks = 0; ks < 5; ks++) {
            bf16x8 b = *(const bf16x8*)(bp + ks * 32);
            acc[nt] = mfma16(af[ks], b, acc[nt]);
        }
    }
    // bias + relu -> hs (C/D layout: col=lane&15, row=quad*4+reg)
    #pragma unroll
    for (int nt = 0; nt < 8; nt++) {
        int col = nt * 16 + l15;
        float bb = b1f[col];
        #pragma unroll
        for (int r = 0; r < 4; r++) {
            float v = fmaxf(acc[nt][r] + bb, 0.f);
            hs[(wv * 16 + quad * 4 + r) * 136 + col] = (bf16_t)v;
        }
    }
    __syncthreads();

    // ---- GEMM2 ----
    bf16x8 hf[4];
    {
        const bf16_t* hp = hs + (wv * 16 + l15) * 136 + quad * 8;
        #pragma unroll
        for (int ks = 0; ks < 4; ks++) hf[ks] = *(const bf16x8*)(hp + ks * 32);
    }
    floatx4 oa[4];
    #pragma unroll
    for (int nt = 0; nt < 4; nt++) { oa[nt].x = 0.f; oa[nt].y = 0.f; oa[nt].z = 0.f; oa[nt].w = 0.f; }
    #pragma unroll
    for (int nt = 0; nt < 4; nt++) {
        const bf16_t* bp = W2t + (nt * 16 + l15) * 128 + quad * 8;
        #pragma unroll
        for (int ks = 0; ks < 4; ks++) {
            bf16x8 b = *(const bf16x8*)(bp + ks * 32);
            oa[nt] = mfma16(hf[ks], b, oa[nt]);
        }
    }
    // scatter: m[e][col] = oa + b2  ->  atomicAdd agg[dst[e]][col]
    #pragma unroll
    for (int nt = 0; nt < 4; nt++) {
        int col = nt * 16 + l15;
        float bb = b2f[col];
        #pragma unroll
        for (int r = 0; r < 4; r++) {
            int row = wv * 16 + quad * 4 + r;
            atomicAdd(agg + (size_t)didx[row] * 64 + col, oa[nt][r] + bb);
        }
    }
}

// ---------------------------------------------------------------------------
// GRU: 32 nodes/block (8 per wave), fp32 weights direct from d_in ([k][192]).
// In-place safe: block reads its own 32 rows before writing them.
// ---------------------------------------------------------------------------
__global__ __launch_bounds__(256) void gru_kernel(
    const float* __restrict__ agg, const float* __restrict__ h_in,
    float* __restrict__ h_out,
    const float* __restrict__ Wx, const float* __restrict__ Wh,
    const float* __restrict__ bg)
{
    __shared__ float sa[32][64];
    __shared__ float shd[32][64];
    const int tid = threadIdx.x;
    const int nb0 = blockIdx.x * 32;

    for (int idx = tid; idx < 32 * 16; idx += 256) {
        int i = idx >> 4, c = (idx & 15) * 4;
        int n = nb0 + i;
        float4 av = make_float4(0.f, 0.f, 0.f, 0.f);
        float4 hv = make_float4(0.f, 0.f, 0.f, 0.f);
        if (n < NN) {
            av = *(const float4*)(agg + (size_t)n * 64 + c);
            hv = *(const float4*)(h_in + (size_t)n * 64 + c);
        }
        *(float4*)&sa[i][c] = av;
        *(float4*)&shd[i][c] = hv;
    }
    __syncthreads();

    const int j  = tid & 63;
    const int wv = tid >> 6;

    float az[8], ar[8], ah[8], bz[8], br_[8], bh[8];
    #pragma unroll
    for (int ii = 0; ii < 8; ii++) { az[ii]=0.f; ar[ii]=0.f; ah[ii]=0.f; bz[ii]=0.f; br_[ii]=0.f; bh[ii]=0.f; }

    for (int k0 = 0; k0 < 64; k0 += 2) {
        float2 a2[8], h2[8];
        #pragma unroll
        for (int ii = 0; ii < 8; ii++) {
            a2[ii] = *(const float2*)&sa[wv * 8 + ii][k0];
            h2[ii] = *(const float2*)&shd[wv * 8 + ii][k0];
        }
        #pragma unroll
        for (int kk = 0; kk < 2; kk++) {
            int k = k0 + kk;
            float wxz = Wx[k * 192 + j];
            float wxr = Wx[k * 192 + 64 + j];
            float wxh = Wx[k * 192 + 128 + j];
            float whz = Wh[k * 192 + j];
            float whr = Wh[k * 192 + 64 + j];
            float whh = Wh[k * 192 + 128 + j];
            #pragma unroll
            for (int ii = 0; ii < 8; ii++) {
                float a  = kk ? a2[ii].y : a2[ii].x;
                float hv = kk ? h2[ii].y : h2[ii].x;
                az[ii]  = fmaf(a,  wxz, az[ii]);
                ar[ii]  = fmaf(a,  wxr, ar[ii]);
                ah[ii]  = fmaf(a,  wxh, ah[ii]);
                bz[ii]  = fmaf(hv, whz, bz[ii]);
                br_[ii] = fmaf(hv, whr, br_[ii]);
                bh[ii]  = fmaf(hv, whh, bh[ii]);
            }
        }
    }

    float g0 = bg[j], g1 = bg[64 + j], g2 = bg[128 + j];
    #pragma unroll
    for (int ii = 0; ii < 8; ii++) {
        int n = nb0 + wv * 8 + ii;
        float z  = sigm_f(az[ii] + g0 + bz[ii]);
        float r  = sigm_f(ar[ii] + g1 + br_[ii]);
        float hc = tanh_f(ah[ii] + g2 + r * bh[ii]);
        float hold = shd[wv * 8 + ii][j];
        float hnew = z * hold + (1.f - z) * hc;
        if (n < NN) h_out[(size_t)n * 64 + j] = hnew;
    }
}

// ---------------------------------------------------------------------------
// readout: out[n] = relu(h@Wr1 + br1) @ Wr2 + br2 ; 32 nodes/block, fp32.
// ---------------------------------------------------------------------------
__global__ __launch_bounds__(256) void readout_kernel(
    const float* __restrict__ h, const float* __restrict__ Wr1,
    const float* __restrict__ br1, const float* __restrict__ Wr2,
    const float* __restrict__ br2, float* __restrict__ out)
{
    __shared__ float shd[32][64];
    const int tid = threadIdx.x;
    const int nb0 = blockIdx.x * 32;

    for (int idx = tid; idx < 32 * 16; idx += 256) {
        int i = idx >> 4, c = (idx & 15) * 4;
        int n = nb0 + i;
        float4 hv = make_float4(0.f, 0.f, 0.f, 0.f);
        if (n < NN) hv = *(const float4*)(h + (size_t)n * 64 + c);
        *(float4*)&shd[i][c] = hv;
    }
    __syncthreads();

    const int j  = tid & 63;
    const int wv = tid >> 6;

    float c0[8], c1[8];
    #pragma unroll
    for (int ii = 0; ii < 8; ii++) { c0[ii] = 0.f; c1[ii] = 0.f; }

    for (int k0 = 0; k0 < 64; k0 += 2) {
        float2 h2[8];
        #pragma unroll
        for (int ii = 0; ii < 8; ii++) h2[ii] = *(const float2*)&shd[wv * 8 + ii][k0];
        #pragma unroll
        for (int kk = 0; kk < 2; kk++) {
            int k = k0 + kk;
            float w0 = Wr1[k * 128 + j];
            float w1 = Wr1[k * 128 + 64 + j];
            #pragma unroll
            for (int ii = 0; ii < 8; ii++) {
                float hv = kk ? h2[ii].y : h2[ii].x;
                c0[ii] = fmaf(hv, w0, c0[ii]);
                c1[ii] = fmaf(hv, w1, c1[ii]);
            }
        }
    }

    float r2a = Wr2[j], r2b = Wr2[64 + j];
    float bb0 = br1[j], bb1 = br1[64 + j];
    float br2v = br2[0];
    #pragma unroll
    for (int ii = 0; ii < 8; ii++) {
        float p = fmaxf(c0[ii] + bb0, 0.f) * r2a + fmaxf(c1[ii] + bb1, 0.f) * r2b;
        #pragma unroll
        for (int m = 32; m >= 1; m >>= 1) p += __shfl_xor(p, m, 64);
        if (j == 0) {
            int n = nb0 + wv * 8 + ii;
            if (n < NN) out[n] = p + br2v;
        }
    }
}

// ---------------------------------------------------------------------------
extern "C" void kernel_launch(void* const* d_in, const int* in_sizes, int n_in,
                              void* d_out, int out_size, void* d_ws, size_t ws_size,
                              hipStream_t stream)
{
    const float* nf  = (const float*)d_in[0];
    const float* ef  = (const float*)d_in[1];
    const int* esrc  = (const int*)d_in[2];
    const int* edst  = (const int*)d_in[3];
    const float* Wm1 = (const float*)d_in[4];
    const float* bm1 = (const float*)d_in[5];
    const float* Wm2 = (const float*)d_in[6];
    const float* bm2 = (const float*)d_in[7];
    const float* Wx  = (const float*)d_in[8];
    const float* Wh  = (const float*)d_in[9];
    const float* bg  = (const float*)d_in[10];
    const float* Wr1 = (const float*)d_in[11];
    const float* br1 = (const float*)d_in[12];
    const float* Wr2 = (const float*)d_in[13];
    const float* br2 = (const float*)d_in[14];

    char* ws = (char*)d_ws;
    float*  hbuf = (float*)(ws);                    // 12,800,000 B
    float*  agg  = (float*)(ws + 12800000);         // 12,800,000 B
    bf16_t* W1t  = (bf16_t*)(ws + 25600000);        // 40,960 B
    bf16_t* W2t  = (bf16_t*)(ws + 25640960);        // 16,384 B

    prep_kernel<<<112, 256, 0, stream>>>(Wm1, Wm2, W1t, W2t);

    for (int t = 0; t < 2; t++) {
        const float* h_in = (t == 0) ? nf : hbuf;
        hipMemsetAsync(agg, 0, (size_t)NN * 64 * 4, stream);
        edge_kernel<<<NE / 64, 256, 0, stream>>>(h_in, ef, esrc, edst, W1t, W2t,
                                                 bm1, bm2, agg);
        gru_kernel<<<(NN + 31) / 32, 256, 0, stream>>>(agg, h_in, hbuf, Wx, Wh, bg);
    }
    readout_kernel<<<(NN + 31) / 32, 256, 0, stream>>>(hbuf, Wr1, br1, Wr2, br2,
                                                       (float*)d_out);
}

// Round 3
// 530.426 us; speedup vs baseline: 1.0875x; 1.0875x over previous
//
#include <hip/hip_runtime.h>
#include <hip/hip_bf16.h>

#define NN 50000
#define NE 400000

typedef __bf16 bf16_t;
typedef __bf16 bf16x8 __attribute__((ext_vector_type(8)));
typedef float  floatx4 __attribute__((ext_vector_type(4)));

static __device__ __forceinline__ floatx4 mfma16(bf16x8 a, bf16x8 b, floatx4 c) {
    return __builtin_amdgcn_mfma_f32_16x16x32_bf16(a, b, c, 0, 0, 0);
}

static __device__ __forceinline__ float sigm_f(float x) {
    return 1.f / (1.f + __expf(-x));
}
static __device__ __forceinline__ float tanh_f(float x) {
    return 1.f - 2.f / (__expf(2.f * x) + 1.f);
}

static __device__ __forceinline__ bf16x8 cvt8(const float* sp) {
    float4 f0 = *(const float4*)sp;
    float4 f1 = *(const float4*)(sp + 4);
    bf16x8 v;
    v[0] = (bf16_t)f0.x; v[1] = (bf16_t)f0.y; v[2] = (bf16_t)f0.z; v[3] = (bf16_t)f0.w;
    v[4] = (bf16_t)f1.x; v[5] = (bf16_t)f1.y; v[6] = (bf16_t)f1.z; v[7] = (bf16_t)f1.w;
    return v;
}

// ---------------------------------------------------------------------------
// prep: transpose fp32 weights -> bf16 W1t[128][160] (k-padded), W2t[64][128].
// ---------------------------------------------------------------------------
__global__ __launch_bounds__(256) void prep_kernel(
    const float* __restrict__ Wm1, const float* __restrict__ Wm2,
    bf16_t* __restrict__ W1t, bf16_t* __restrict__ W2t)
{
    int u = blockIdx.x * 256 + threadIdx.x;
    if (u < 20480) {            // W1t[n*160+k] = (k<136) ? Wm1[k*128+n] : 0
        int n = u / 160, k = u - n * 160;
        W1t[u] = (k < 136) ? (bf16_t)Wm1[k * 128 + n] : (bf16_t)0.f;
        return;
    }
    u -= 20480;
    if (u < 8192) {             // W2t[n*128+k] = Wm2[k*64+n]
        int n = u / 128, k = u - n * 128;
        W2t[u] = (bf16_t)Wm2[k * 64 + n];
    }
}

// ---------------------------------------------------------------------------
// edge kernel v2: 64 edges/block, 16 edges/wave. A-fragments gathered
// directly global->register (fp32->bf16 cvt in regs), hidden tile is a
// per-wave private LDS stripe (no inter-wave dependency -> 1 barrier only).
// GEMM1: [16 x 160] x [160 x 128] -> relu -> hs stripe (bf16)
// GEMM2: [16 x 128] x [128 x 64]  -> + b2 -> atomicAdd scatter to agg (fp32)
// ---------------------------------------------------------------------------
__global__ __launch_bounds__(256) void edge_kernel(
    const float* __restrict__ h, const float* __restrict__ ef,
    const int* __restrict__ esrc, const int* __restrict__ edst,
    const bf16_t* __restrict__ W1t, const bf16_t* __restrict__ W2t,
    const float* __restrict__ b1f, const float* __restrict__ b2f,
    float* __restrict__ agg)
{
    // pitch 136 bf16 = 272 B: b128 reads land on 2-way bank aliasing (free)
    __shared__ __attribute__((aligned(16))) bf16_t hs[4][16 * 136];
    __shared__ int sidx[64];
    __shared__ int didx[64];

    const int tid = threadIdx.x;
    const int e0  = blockIdx.x * 64;

    if (tid < 64) { sidx[tid] = esrc[e0 + tid]; didx[tid] = edst[e0 + tid]; }
    __syncthreads();

    const int lane = tid & 63;
    const int wv   = tid >> 6;       // wave -> edge rows [wv*16, wv*16+16)
    const int l15  = lane & 15;
    const int quad = lane >> 4;
    const int row  = wv * 16 + l15;  // edge row whose A-frag this lane loads

    // ---- A fragments: A[m=l15][k=quad*8+j+ks*32], k-space [src64|dst64|ef8|pad24]
    bf16x8 af[5];
    {
        const float* sp0 = h + (size_t)sidx[row] * 64 + quad * 8;
        const float* sp1 = h + (size_t)didx[row] * 64 + quad * 8;
        af[0] = cvt8(sp0);
        af[1] = cvt8(sp0 + 32);
        af[2] = cvt8(sp1);
        af[3] = cvt8(sp1 + 32);
        if (quad == 0) {
            af[4] = cvt8(ef + (size_t)(e0 + row) * 8);
        } else {
            #pragma unroll
            for (int q = 0; q < 8; q++) af[4][q] = (bf16_t)0.f;
        }
    }

    // ---- GEMM1 ----
    floatx4 acc[8];
    #pragma unroll
    for (int nt = 0; nt < 8; nt++) { acc[nt].x = 0.f; acc[nt].y = 0.f; acc[nt].z = 0.f; acc[nt].w = 0.f; }
    #pragma unroll
    for (int nt = 0; nt < 8; nt++) {
        const bf16_t* bp = W1t + (nt * 16 + l15) * 160 + quad * 8;
        #pragma unroll
        for (int ks = 0; ks < 5; ks++) {
            bf16x8 b = *(const bf16x8*)(bp + ks * 32);
            acc[nt] = mfma16(af[ks], b, acc[nt]);
        }
    }
    // bias + relu -> per-wave hs stripe (C/D: col=l15, local row=quad*4+r)
    #pragma unroll
    for (int nt = 0; nt < 8; nt++) {
        int col = nt * 16 + l15;
        float bb = b1f[col];
        #pragma unroll
        for (int r = 0; r < 4; r++) {
            float v = fmaxf(acc[nt][r] + bb, 0.f);
            hs[wv][(quad * 4 + r) * 136 + col] = (bf16_t)v;
        }
    }
    // same-wave LDS write->read: compiler inserts lgkmcnt wait; no barrier.

    // ---- GEMM2 ----
    bf16x8 hf[4];
    {
        const bf16_t* hp = hs[wv] + l15 * 136 + quad * 8;
        #pragma unroll
        for (int ks = 0; ks < 4; ks++) hf[ks] = *(const bf16x8*)(hp + ks * 32);
    }
    floatx4 oa[4];
    #pragma unroll
    for (int nt = 0; nt < 4; nt++) { oa[nt].x = 0.f; oa[nt].y = 0.f; oa[nt].z = 0.f; oa[nt].w = 0.f; }
    #pragma unroll
    for (int nt = 0; nt < 4; nt++) {
        const bf16_t* bp = W2t + (nt * 16 + l15) * 128 + quad * 8;
        #pragma unroll
        for (int ks = 0; ks < 4; ks++) {
            bf16x8 b = *(const bf16x8*)(bp + ks * 32);
            oa[nt] = mfma16(hf[ks], b, oa[nt]);
        }
    }
    // scatter: m[e][col] = oa + b2  ->  atomicAdd agg[dst[e]][col]
    #pragma unroll
    for (int nt = 0; nt < 4; nt++) {
        int col = nt * 16 + l15;
        float bb = b2f[col];
        #pragma unroll
        for (int r = 0; r < 4; r++) {
            int orow = wv * 16 + quad * 4 + r;
            atomicAdd(agg + (size_t)didx[orow] * 64 + col, oa[nt][r] + bb);
        }
    }
}

// ---------------------------------------------------------------------------
// GRU: 32 nodes/block (8 per wave), fp32 weights direct from d_in ([k][192]).
// k-loop pinned to unroll 1 to keep VGPR pressure bounded (R1: auto-unroll
// spilled in the sibling readout kernel).
// ---------------------------------------------------------------------------
__global__ __launch_bounds__(256) void gru_kernel(
    const float* __restrict__ agg, const float* __restrict__ h_in,
    float* __restrict__ h_out,
    const float* __restrict__ Wx, const float* __restrict__ Wh,
    const float* __restrict__ bg)
{
    __shared__ float sa[32][64];
    __shared__ float shd[32][64];
    const int tid = threadIdx.x;
    const int nb0 = blockIdx.x * 32;

    for (int idx = tid; idx < 32 * 16; idx += 256) {
        int i = idx >> 4, c = (idx & 15) * 4;
        int n = nb0 + i;
        float4 av = make_float4(0.f, 0.f, 0.f, 0.f);
        float4 hv = make_float4(0.f, 0.f, 0.f, 0.f);
        if (n < NN) {
            av = *(const float4*)(agg + (size_t)n * 64 + c);
            hv = *(const float4*)(h_in + (size_t)n * 64 + c);
        }
        *(float4*)&sa[i][c] = av;
        *(float4*)&shd[i][c] = hv;
    }
    __syncthreads();

    const int j  = tid & 63;
    const int wv = tid >> 6;

    float az[8], ar[8], ah[8], bz[8], br_[8], bh[8];
    #pragma unroll
    for (int ii = 0; ii < 8; ii++) { az[ii]=0.f; ar[ii]=0.f; ah[ii]=0.f; bz[ii]=0.f; br_[ii]=0.f; bh[ii]=0.f; }

    #pragma unroll 1
    for (int k0 = 0; k0 < 64; k0 += 2) {
        float2 a2[8], h2[8];
        #pragma unroll
        for (int ii = 0; ii < 8; ii++) {
            a2[ii] = *(const float2*)&sa[wv * 8 + ii][k0];
            h2[ii] = *(const float2*)&shd[wv * 8 + ii][k0];
        }
        #pragma unroll
        for (int kk = 0; kk < 2; kk++) {
            int k = k0 + kk;
            float wxz = Wx[k * 192 + j];
            float wxr = Wx[k * 192 + 64 + j];
            float wxh = Wx[k * 192 + 128 + j];
            float whz = Wh[k * 192 + j];
            float whr = Wh[k * 192 + 64 + j];
            float whh = Wh[k * 192 + 128 + j];
            #pragma unroll
            for (int ii = 0; ii < 8; ii++) {
                float a  = kk ? a2[ii].y : a2[ii].x;
                float hv = kk ? h2[ii].y : h2[ii].x;
                az[ii]  = fmaf(a,  wxz, az[ii]);
                ar[ii]  = fmaf(a,  wxr, ar[ii]);
                ah[ii]  = fmaf(a,  wxh, ah[ii]);
                bz[ii]  = fmaf(hv, whz, bz[ii]);
                br_[ii] = fmaf(hv, whr, br_[ii]);
                bh[ii]  = fmaf(hv, whh, bh[ii]);
            }
        }
    }

    float g0 = bg[j], g1 = bg[64 + j], g2 = bg[128 + j];
    #pragma unroll
    for (int ii = 0; ii < 8; ii++) {
        int n = nb0 + wv * 8 + ii;
        float z  = sigm_f(az[ii] + g0 + bz[ii]);
        float r  = sigm_f(ar[ii] + g1 + br_[ii]);
        float hc = tanh_f(ah[ii] + g2 + r * bh[ii]);
        float hold = shd[wv * 8 + ii][j];
        float hnew = z * hold + (1.f - z) * hc;
        if (n < NN) h_out[(size_t)n * 64 + j] = hnew;
    }
}

// ---------------------------------------------------------------------------
// readout: out[n] = relu(h@Wr1 + br1) @ Wr2 + br2 ; 32 nodes/block, fp32.
// k-loop pinned to unroll 1 (R1 auto-unroll -> 256 VGPR + 118 MB spill).
// ---------------------------------------------------------------------------
__global__ __launch_bounds__(256) void readout_kernel(
    const float* __restrict__ h, const float* __restrict__ Wr1,
    const float* __restrict__ br1, const float* __restrict__ Wr2,
    const float* __restrict__ br2, float* __restrict__ out)
{
    __shared__ float shd[32][64];
    const int tid = threadIdx.x;
    const int nb0 = blockIdx.x * 32;

    for (int idx = tid; idx < 32 * 16; idx += 256) {
        int i = idx >> 4, c = (idx & 15) * 4;
        int n = nb0 + i;
        float4 hv = make_float4(0.f, 0.f, 0.f, 0.f);
        if (n < NN) hv = *(const float4*)(h + (size_t)n * 64 + c);
        *(float4*)&shd[i][c] = hv;
    }
    __syncthreads();

    const int j  = tid & 63;
    const int wv = tid >> 6;

    float c0[8], c1[8];
    #pragma unroll
    for (int ii = 0; ii < 8; ii++) { c0[ii] = 0.f; c1[ii] = 0.f; }

    #pragma unroll 1
    for (int k0 = 0; k0 < 64; k0 += 2) {
        float2 h2[8];
        #pragma unroll
        for (int ii = 0; ii < 8; ii++) h2[ii] = *(const float2*)&shd[wv * 8 + ii][k0];
        #pragma unroll
        for (int kk = 0; kk < 2; kk++) {
            int k = k0 + kk;
            float w0 = Wr1[k * 128 + j];
            float w1 = Wr1[k * 128 + 64 + j];
            #pragma unroll
            for (int ii = 0; ii < 8; ii++) {
                float hv = kk ? h2[ii].y : h2[ii].x;
                c0[ii] = fmaf(hv, w0, c0[ii]);
                c1[ii] = fmaf(hv, w1, c1[ii]);
            }
        }
    }

    float r2a = Wr2[j], r2b = Wr2[64 + j];
    float bb0 = br1[j], bb1 = br1[64 + j];
    float br2v = br2[0];
    #pragma unroll
    for (int ii = 0; ii < 8; ii++) {
        float p = fmaxf(c0[ii] + bb0, 0.f) * r2a + fmaxf(c1[ii] + bb1, 0.f) * r2b;
        #pragma unroll
        for (int m = 32; m >= 1; m >>= 1) p += __shfl_xor(p, m, 64);
        if (j == 0) {
            int n = nb0 + wv * 8 + ii;
            if (n < NN) out[n] = p + br2v;
        }
    }
}

// ---------------------------------------------------------------------------
extern "C" void kernel_launch(void* const* d_in, const int* in_sizes, int n_in,
                              void* d_out, int out_size, void* d_ws, size_t ws_size,
                              hipStream_t stream)
{
    const float* nf  = (const float*)d_in[0];
    const float* ef  = (const float*)d_in[1];
    const int* esrc  = (const int*)d_in[2];
    const int* edst  = (const int*)d_in[3];
    const float* Wm1 = (const float*)d_in[4];
    const float* bm1 = (const float*)d_in[5];
    const float* Wm2 = (const float*)d_in[6];
    const float* bm2 = (const float*)d_in[7];
    const float* Wx  = (const float*)d_in[8];
    const float* Wh  = (const float*)d_in[9];
    const float* bg  = (const float*)d_in[10];
    const float* Wr1 = (const float*)d_in[11];
    const float* br1 = (const float*)d_in[12];
    const float* Wr2 = (const float*)d_in[13];
    const float* br2 = (const float*)d_in[14];

    char* ws = (char*)d_ws;
    float*  hbuf = (float*)(ws);                    // 12,800,000 B
    float*  agg  = (float*)(ws + 12800000);         // 12,800,000 B
    bf16_t* W1t  = (bf16_t*)(ws + 25600000);        // 40,960 B
    bf16_t* W2t  = (bf16_t*)(ws + 25640960);        // 16,384 B

    prep_kernel<<<112, 256, 0, stream>>>(Wm1, Wm2, W1t, W2t);

    for (int t = 0; t < 2; t++) {
        const float* h_in = (t == 0) ? nf : hbuf;
        hipMemsetAsync(agg, 0, (size_t)NN * 64 * 4, stream);
        edge_kernel<<<NE / 64, 256, 0, stream>>>(h_in, ef, esrc, edst, W1t, W2t,
                                                 bm1, bm2, agg);
        gru_kernel<<<(NN + 31) / 32, 256, 0, stream>>>(agg, h_in, hbuf, Wx, Wh, bg);
    }
    readout_kernel<<<(NN + 31) / 32, 256, 0, stream>>>(hbuf, Wr1, br1, Wr2, br2,
                                                       (float*)d_out);
}

// Round 4
// 490.649 us; speedup vs baseline: 1.1757x; 1.0811x over previous
//
#include <hip/hip_runtime.h>
#include <hip/hip_bf16.h>

#define NN 50000
#define NE 400000
#define NCH 196            // ceil(50176/256) scan chunks
#define NPAD 50176         // NCH*256

typedef __bf16 bf16_t;
typedef __bf16 bf16x8 __attribute__((ext_vector_type(8)));
typedef float  floatx4 __attribute__((ext_vector_type(4)));

static __device__ __forceinline__ floatx4 mfma16(bf16x8 a, bf16x8 b, floatx4 c) {
    return __builtin_amdgcn_mfma_f32_16x16x32_bf16(a, b, c, 0, 0, 0);
}
static __device__ __forceinline__ float sigm_f(float x) {
    return 1.f / (1.f + __expf(-x));
}
static __device__ __forceinline__ float tanh_f(float x) {
    return 1.f - 2.f / (__expf(2.f * x) + 1.f);
}
static __device__ __forceinline__ bf16x8 cvt8(const float* sp) {
    float4 f0 = *(const float4*)sp;
    float4 f1 = *(const float4*)(sp + 4);
    bf16x8 v;
    v[0] = (bf16_t)f0.x; v[1] = (bf16_t)f0.y; v[2] = (bf16_t)f0.z; v[3] = (bf16_t)f0.w;
    v[4] = (bf16_t)f1.x; v[5] = (bf16_t)f1.y; v[6] = (bf16_t)f1.z; v[7] = (bf16_t)f1.w;
    return v;
}

// ---------------------------------------------------------------------------
// prep: weight transposes. W1t[128][160] bf16 (k-pad), W2t[64][128] bf16,
// Wxt[192][64] bf16, Wht[192][64] bf16.
// ---------------------------------------------------------------------------
__global__ __launch_bounds__(256) void prep_kernel(
    const float* __restrict__ Wm1, const float* __restrict__ Wm2,
    const float* __restrict__ Wx,  const float* __restrict__ Wh,
    bf16_t* __restrict__ W1t, bf16_t* __restrict__ W2t,
    bf16_t* __restrict__ Wxt, bf16_t* __restrict__ Wht)
{
    int u = blockIdx.x * 256 + threadIdx.x;
    if (u < 20480) {
        int n = u / 160, k = u - n * 160;
        W1t[u] = (k < 136) ? (bf16_t)Wm1[k * 128 + n] : (bf16_t)0.f;
        return;
    }
    u -= 20480;
    if (u < 8192) {
        int n = u / 128, k = u - n * 128;
        W2t[u] = (bf16_t)Wm2[k * 64 + n];
        return;
    }
    u -= 8192;
    if (u < 12288) {
        int n = u >> 6, k = u & 63;
        Wxt[u] = (bf16_t)Wx[k * 192 + n];
        return;
    }
    u -= 12288;
    if (u < 12288) {
        int n = u >> 6, k = u & 63;
        Wht[u] = (bf16_t)Wh[k * 192 + n];
    }
}

// ---------------------------------------------------------------------------
// CSR build: hist -> scan (3 kernels) -> scatter (permute srcs/dsts/ef)
// ---------------------------------------------------------------------------
__global__ __launch_bounds__(256) void hist_kernel(
    const int* __restrict__ edst, int* __restrict__ deg)
{
    int e = blockIdx.x * 256 + threadIdx.x;
    if (e < NE) atomicAdd(&deg[edst[e]], 1);
}

__global__ __launch_bounds__(256) void scanA_kernel(
    const int* __restrict__ deg, int* __restrict__ chunkSums)
{
    __shared__ int s[256];
    int i = blockIdx.x * 256 + threadIdx.x;
    s[threadIdx.x] = deg[i];
    __syncthreads();
    for (int st = 128; st >= 1; st >>= 1) {
        if (threadIdx.x < st) s[threadIdx.x] += s[threadIdx.x + st];
        __syncthreads();
    }
    if (threadIdx.x == 0) chunkSums[blockIdx.x] = s[0];
}

__global__ __launch_bounds__(256) void scanB_kernel(
    const int* __restrict__ chunkSums, int* __restrict__ chunkOff)
{
    __shared__ int s[256];
    int t = threadIdx.x;
    int v = (t < NCH) ? chunkSums[t] : 0;
    s[t] = v;
    __syncthreads();
    for (int st = 1; st < 256; st <<= 1) {
        int add = (t >= st) ? s[t - st] : 0;
        __syncthreads();
        s[t] += add;
        __syncthreads();
    }
    if (t < NCH) chunkOff[t] = s[t] - v;   // exclusive
}

__global__ __launch_bounds__(256) void scanC_kernel(
    const int* __restrict__ deg, const int* __restrict__ chunkOff,
    int* __restrict__ cursor)
{
    __shared__ int s[256];
    int t = threadIdx.x;
    int i = blockIdx.x * 256 + t;
    int v = deg[i];
    s[t] = v;
    __syncthreads();
    for (int st = 1; st < 256; st <<= 1) {
        int add = (t >= st) ? s[t - st] : 0;
        __syncthreads();
        s[t] += add;
        __syncthreads();
    }
    cursor[i] = chunkOff[blockIdx.x] + s[t] - v;   // exclusive
}

__global__ __launch_bounds__(256) void scatter_kernel(
    const int* __restrict__ esrc, const int* __restrict__ edst,
    const float* __restrict__ ef,
    int* __restrict__ cursor, int* __restrict__ srcs, int* __restrict__ dsts,
    float* __restrict__ efp)
{
    int e = blockIdx.x * 256 + threadIdx.x;
    if (e >= NE) return;
    int d = edst[e];
    int p = atomicAdd(&cursor[d], 1);
    srcs[p] = esrc[e];
    dsts[p] = d;
    float4 a = *(const float4*)(ef + (size_t)e * 8);
    float4 b = *(const float4*)(ef + (size_t)e * 8 + 4);
    *(float4*)(efp + (size_t)p * 8)     = a;
    *(float4*)(efp + (size_t)p * 8 + 4) = b;
}

// ---------------------------------------------------------------------------
// edge kernel v3: 64 dst-sorted edges/block, 16/wave. MFMA pipeline as v2,
// epilogue writes m (+b2) to fp32 LDS tile; segmented run-reduction emits
// one atomicAdd per (dst-run, col) instead of per (edge, col).
// ---------------------------------------------------------------------------
__global__ __launch_bounds__(256) void edge_kernel(
    const float* __restrict__ h, const float* __restrict__ efp,
    const int* __restrict__ srcs, const int* __restrict__ dsts,
    const bf16_t* __restrict__ W1t, const bf16_t* __restrict__ W2t,
    const float* __restrict__ b1f, const float* __restrict__ b2f,
    float* __restrict__ agg)
{
    __shared__ __attribute__((aligned(16))) bf16_t hs[4][16 * 136]; // 17408 B
    __shared__ __attribute__((aligned(16))) float  ms[64 * 68];     // 17408 B
    __shared__ int sidx[64];
    __shared__ int didx[64];

    const int tid = threadIdx.x;
    const int e0  = blockIdx.x * 64;

    if (tid < 64) { sidx[tid] = srcs[e0 + tid]; didx[tid] = dsts[e0 + tid]; }
    __syncthreads();

    const int lane = tid & 63;
    const int wv   = tid >> 6;
    const int l15  = lane & 15;
    const int quad = lane >> 4;
    const int row  = wv * 16 + l15;

    // A fragments: k-space [src64|dst64|ef8|pad24]
    bf16x8 af[5];
    {
        const float* sp0 = h + (size_t)sidx[row] * 64 + quad * 8;
        const float* sp1 = h + (size_t)didx[row] * 64 + quad * 8;
        af[0] = cvt8(sp0);
        af[1] = cvt8(sp0 + 32);
        af[2] = cvt8(sp1);
        af[3] = cvt8(sp1 + 32);
        if (quad == 0) {
            af[4] = cvt8(efp + (size_t)(e0 + row) * 8);
        } else {
            #pragma unroll
            for (int q = 0; q < 8; q++) af[4][q] = (bf16_t)0.f;
        }
    }

    // ---- GEMM1 ----
    floatx4 acc[8];
    #pragma unroll
    for (int nt = 0; nt < 8; nt++) { acc[nt].x = 0.f; acc[nt].y = 0.f; acc[nt].z = 0.f; acc[nt].w = 0.f; }
    #pragma unroll
    for (int nt = 0; nt < 8; nt++) {
        const bf16_t* bp = W1t + (nt * 16 + l15) * 160 + quad * 8;
        #pragma unroll
        for (int ks = 0; ks < 5; ks++) {
            bf16x8 b = *(const bf16x8*)(bp + ks * 32);
            acc[nt] = mfma16(af[ks], b, acc[nt]);
        }
    }
    #pragma unroll
    for (int nt = 0; nt < 8; nt++) {
        int col = nt * 16 + l15;
        float bb = b1f[col];
        #pragma unroll
        for (int r = 0; r < 4; r++) {
            float v = fmaxf(acc[nt][r] + bb, 0.f);
            hs[wv][(quad * 4 + r) * 136 + col] = (bf16_t)v;
        }
    }
    // same-wave write->read, compiler inserts lgkmcnt wait

    // ---- GEMM2 ----
    bf16x8 hf[4];
    {
        const bf16_t* hp = hs[wv] + l15 * 136 + quad * 8;
        #pragma unroll
        for (int ks = 0; ks < 4; ks++) hf[ks] = *(const bf16x8*)(hp + ks * 32);
    }
    floatx4 oa[4];
    #pragma unroll
    for (int nt = 0; nt < 4; nt++) { oa[nt].x = 0.f; oa[nt].y = 0.f; oa[nt].z = 0.f; oa[nt].w = 0.f; }
    #pragma unroll
    for (int nt = 0; nt < 4; nt++) {
        const bf16_t* bp = W2t + (nt * 16 + l15) * 128 + quad * 8;
        #pragma unroll
        for (int ks = 0; ks < 4; ks++) {
            bf16x8 b = *(const bf16x8*)(bp + ks * 32);
            oa[nt] = mfma16(hf[ks], b, oa[nt]);
        }
    }
    // m (+b2) -> LDS tile [row][col] pitch 68 (2-way bank alias: free)
    #pragma unroll
    for (int nt = 0; nt < 4; nt++) {
        int col = nt * 16 + l15;
        float bb = b2f[col];
        #pragma unroll
        for (int r = 0; r < 4; r++) {
            int orow = wv * 16 + quad * 4 + r;
            ms[orow * 68 + col] = oa[nt][r] + bb;
        }
    }
    __syncthreads();

    // segmented run reduction: 64 cols x 4 segments of 16 rows
    {
        const int col = tid & 63;
        const int seg = tid >> 6;
        const int r0  = seg * 16;
        int dprev = didx[r0];
        float sum = ms[r0 * 68 + col];
        #pragma unroll 1
        for (int r = r0 + 1; r < r0 + 16; r++) {
            int d = didx[r];
            float v = ms[r * 68 + col];
            if (d == dprev) sum += v;
            else {
                atomicAdd(agg + (size_t)dprev * 64 + col, sum);
                dprev = d; sum = v;
            }
        }
        atomicAdd(agg + (size_t)dprev * 64 + col, sum);
    }
}

// ---------------------------------------------------------------------------
// GRU v2 (MFMA): 64 nodes/block, 16/wave. acc_z/acc_r = agg@Wx + h@Wh fused;
// candidate keeps x-part and h-part separate (reset gate scales only hh).
// ---------------------------------------------------------------------------
__global__ __launch_bounds__(256) void gru_kernel(
    const float* __restrict__ agg, const float* __restrict__ h_in,
    float* __restrict__ h_out,
    const bf16_t* __restrict__ Wxt, const bf16_t* __restrict__ Wht,
    const float* __restrict__ bg)
{
    __shared__ __attribute__((aligned(16))) float shd[64 * 68];   // 17408 B
    const int tid = threadIdx.x;
    const int n0  = blockIdx.x * 64;

    for (int idx = tid; idx < 64 * 16; idx += 256) {
        int i = idx >> 4, c = (idx & 15) * 4;
        int n = n0 + i; if (n >= NN) n = NN - 1;
        *(float4*)&shd[i * 68 + c] = *(const float4*)(h_in + (size_t)n * 64 + c);
    }
    __syncthreads();

    const int lane = tid & 63;
    const int wv   = tid >> 6;
    const int l15  = lane & 15;
    const int quad = lane >> 4;
    const int rowA = wv * 16 + l15;
    int nA = n0 + rowA; if (nA >= NN) nA = NN - 1;

    bf16x8 ax[2], ah[2];
    ax[0] = cvt8(agg + (size_t)nA * 64 + quad * 8);
    ax[1] = cvt8(agg + (size_t)nA * 64 + quad * 8 + 32);
    {
        const float* hp = shd + rowA * 68 + quad * 8;
        ah[0] = cvt8(hp);
        ah[1] = cvt8(hp + 32);
    }

    floatx4 az[4], ar[4], axh[4], ahh[4];
    #pragma unroll
    for (int nt = 0; nt < 4; nt++) {
        az[nt].x=0.f; az[nt].y=0.f; az[nt].z=0.f; az[nt].w=0.f;
        ar[nt].x=0.f; ar[nt].y=0.f; ar[nt].z=0.f; ar[nt].w=0.f;
        axh[nt].x=0.f; axh[nt].y=0.f; axh[nt].z=0.f; axh[nt].w=0.f;
        ahh[nt].x=0.f; ahh[nt].y=0.f; ahh[nt].z=0.f; ahh[nt].w=0.f;
    }
    #pragma unroll
    for (int nt = 0; nt < 4; nt++) {
        const bf16_t* bx_z = Wxt + (nt * 16 + l15) * 64 + quad * 8;
        const bf16_t* bh_z = Wht + (nt * 16 + l15) * 64 + quad * 8;
        const bf16_t* bx_r = bx_z + 64 * 64;
        const bf16_t* bh_r = bh_z + 64 * 64;
        const bf16_t* bx_h = bx_z + 128 * 64;
        const bf16_t* bh_h = bh_z + 128 * 64;
        az[nt]  = mfma16(ax[0], *(const bf16x8*)bx_z,        az[nt]);
        az[nt]  = mfma16(ax[1], *(const bf16x8*)(bx_z + 32), az[nt]);
        az[nt]  = mfma16(ah[0], *(const bf16x8*)bh_z,        az[nt]);
        az[nt]  = mfma16(ah[1], *(const bf16x8*)(bh_z + 32), az[nt]);
        ar[nt]  = mfma16(ax[0], *(const bf16x8*)bx_r,        ar[nt]);
        ar[nt]  = mfma16(ax[1], *(const bf16x8*)(bx_r + 32), ar[nt]);
        ar[nt]  = mfma16(ah[0], *(const bf16x8*)bh_r,        ar[nt]);
        ar[nt]  = mfma16(ah[1], *(const bf16x8*)(bh_r + 32), ar[nt]);
        axh[nt] = mfma16(ax[0], *(const bf16x8*)bx_h,        axh[nt]);
        axh[nt] = mfma16(ax[1], *(const bf16x8*)(bx_h + 32), axh[nt]);
        ahh[nt] = mfma16(ah[0], *(const bf16x8*)bh_h,        ahh[nt]);
        ahh[nt] = mfma16(ah[1], *(const bf16x8*)(bh_h + 32), ahh[nt]);
    }

    #pragma unroll
    for (int nt = 0; nt < 4; nt++) {
        int j = nt * 16 + l15;
        float bz = bg[j], brr = bg[64 + j], bh = bg[128 + j];
        #pragma unroll
        for (int r = 0; r < 4; r++) {
            int lrow = wv * 16 + quad * 4 + r;
            int n = n0 + lrow;
            float z  = sigm_f(az[nt][r] + bz);
            float rr = sigm_f(ar[nt][r] + brr);
            float hc = tanh_f(axh[nt][r] + bh + rr * ahh[nt][r]);
            float hold = shd[lrow * 68 + j];
            float hnew = z * hold + (1.f - z) * hc;
            if (n < NN) h_out[(size_t)n * 64 + j] = hnew;
        }
    }
}

// ---------------------------------------------------------------------------
// readout: out[n] = relu(h@Wr1 + br1) @ Wr2 + br2 ; 32 nodes/block, fp32.
// k-loop pinned unroll 1 (R1: auto-unroll -> 256 VGPR spill).
// ---------------------------------------------------------------------------
__global__ __launch_bounds__(256) void readout_kernel(
    const float* __restrict__ h, const float* __restrict__ Wr1,
    const float* __restrict__ br1, const float* __restrict__ Wr2,
    const float* __restrict__ br2, float* __restrict__ out)
{
    __shared__ float shd[32][64];
    const int tid = threadIdx.x;
    const int nb0 = blockIdx.x * 32;

    for (int idx = tid; idx < 32 * 16; idx += 256) {
        int i = idx >> 4, c = (idx & 15) * 4;
        int n = nb0 + i;
        float4 hv = make_float4(0.f, 0.f, 0.f, 0.f);
        if (n < NN) hv = *(const float4*)(h + (size_t)n * 64 + c);
        *(float4*)&shd[i][c] = hv;
    }
    __syncthreads();

    const int j  = tid & 63;
    const int wv = tid >> 6;

    float c0[8], c1[8];
    #pragma unroll
    for (int ii = 0; ii < 8; ii++) { c0[ii] = 0.f; c1[ii] = 0.f; }

    #pragma unroll 1
    for (int k0 = 0; k0 < 64; k0 += 2) {
        float2 h2[8];
        #pragma unroll
        for (int ii = 0; ii < 8; ii++) h2[ii] = *(const float2*)&shd[wv * 8 + ii][k0];
        #pragma unroll
        for (int kk = 0; kk < 2; kk++) {
            int k = k0 + kk;
            float w0 = Wr1[k * 128 + j];
            float w1 = Wr1[k * 128 + 64 + j];
            #pragma unroll
            for (int ii = 0; ii < 8; ii++) {
                float hv = kk ? h2[ii].y : h2[ii].x;
                c0[ii] = fmaf(hv, w0, c0[ii]);
                c1[ii] = fmaf(hv, w1, c1[ii]);
            }
        }
    }

    float r2a = Wr2[j], r2b = Wr2[64 + j];
    float bb0 = br1[j], bb1 = br1[64 + j];
    float br2v = br2[0];
    #pragma unroll
    for (int ii = 0; ii < 8; ii++) {
        float p = fmaxf(c0[ii] + bb0, 0.f) * r2a + fmaxf(c1[ii] + bb1, 0.f) * r2b;
        #pragma unroll
        for (int m = 32; m >= 1; m >>= 1) p += __shfl_xor(p, m, 64);
        if (j == 0) {
            int n = nb0 + wv * 8 + ii;
            if (n < NN) out[n] = p + br2v;
        }
    }
}

// ---------------------------------------------------------------------------
extern "C" void kernel_launch(void* const* d_in, const int* in_sizes, int n_in,
                              void* d_out, int out_size, void* d_ws, size_t ws_size,
                              hipStream_t stream)
{
    const float* nf  = (const float*)d_in[0];
    const float* ef  = (const float*)d_in[1];
    const int* esrc  = (const int*)d_in[2];
    const int* edst  = (const int*)d_in[3];
    const float* Wm1 = (const float*)d_in[4];
    const float* bm1 = (const float*)d_in[5];
    const float* Wm2 = (const float*)d_in[6];
    const float* bm2 = (const float*)d_in[7];
    const float* Wx  = (const float*)d_in[8];
    const float* Wh  = (const float*)d_in[9];
    const float* bg  = (const float*)d_in[10];
    const float* Wr1 = (const float*)d_in[11];
    const float* br1 = (const float*)d_in[12];
    const float* Wr2 = (const float*)d_in[13];
    const float* br2 = (const float*)d_in[14];

    char* ws = (char*)d_ws;
    float*  hbuf   = (float*)(ws);                   // 12,800,000
    float*  agg    = (float*)(ws + 12800000);        // 12,800,000
    bf16_t* W1t    = (bf16_t*)(ws + 25600000);       // 40,960
    bf16_t* W2t    = (bf16_t*)(ws + 25640960);       // 16,384
    bf16_t* Wxt    = (bf16_t*)(ws + 25657344);       // 24,576
    bf16_t* Wht    = (bf16_t*)(ws + 25681920);       // 24,576
    int*    srcs   = (int*)(ws + 25706496);          // 1,600,000
    int*    dsts   = (int*)(ws + 27306496);          // 1,600,000
    float*  efp    = (float*)(ws + 28906496);        // 12,800,000
    int*    deg    = (int*)(ws + 41706496);          // 200,704
    int*    cursor = (int*)(ws + 41907200);          // 200,704
    int*    chunkS = (int*)(ws + 42107904);          // 1,024
    int*    chunkO = (int*)(ws + 42108928);          // 1,024

    prep_kernel<<<208, 256, 0, stream>>>(Wm1, Wm2, Wx, Wh, W1t, W2t, Wxt, Wht);

    // CSR build (per launch; same work every call)
    hipMemsetAsync(deg, 0, NPAD * 4, stream);
    hist_kernel<<<(NE + 255) / 256, 256, 0, stream>>>(edst, deg);
    scanA_kernel<<<NCH, 256, 0, stream>>>(deg, chunkS);
    scanB_kernel<<<1, 256, 0, stream>>>(chunkS, chunkO);
    scanC_kernel<<<NCH, 256, 0, stream>>>(deg, chunkO, cursor);
    scatter_kernel<<<(NE + 255) / 256, 256, 0, stream>>>(esrc, edst, ef, cursor,
                                                         srcs, dsts, efp);

    for (int t = 0; t < 2; t++) {
        const float* h_in = (t == 0) ? nf : hbuf;
        hipMemsetAsync(agg, 0, (size_t)NN * 64 * 4, stream);
        edge_kernel<<<NE / 64, 256, 0, stream>>>(h_in, efp, srcs, dsts, W1t, W2t,
                                                 bm1, bm2, agg);
        gru_kernel<<<(NN + 63) / 64, 256, 0, stream>>>(agg, h_in, hbuf, Wxt, Wht, bg);
    }
    readout_kernel<<<(NN + 31) / 32, 256, 0, stream>>>(hbuf, Wr1, br1, Wr2, br2,
                                                       (float*)d_out);
}

// Round 5
// 483.862 us; speedup vs baseline: 1.1922x; 1.0140x over previous
//
#include <hip/hip_runtime.h>
#include <hip/hip_bf16.h>

#define NN 50000
#define NE 400000
#define NTILE 6250         // NE/64 edge tiles
#define NCH 196            // ceil(50176/256) scan chunks
#define NPAD 50176         // NCH*256

typedef __bf16 bf16_t;
typedef __bf16 bf16x8 __attribute__((ext_vector_type(8)));
typedef float  floatx4 __attribute__((ext_vector_type(4)));

static __device__ __forceinline__ floatx4 mfma16(bf16x8 a, bf16x8 b, floatx4 c) {
    return __builtin_amdgcn_mfma_f32_16x16x32_bf16(a, b, c, 0, 0, 0);
}
static __device__ __forceinline__ float sigm_f(float x) {
    return 1.f / (1.f + __expf(-x));
}
static __device__ __forceinline__ float tanh_f(float x) {
    return 1.f - 2.f / (__expf(2.f * x) + 1.f);
}
static __device__ __forceinline__ bf16x8 cvt8(const float* sp) {
    float4 f0 = *(const float4*)sp;
    float4 f1 = *(const float4*)(sp + 4);
    bf16x8 v;
    v[0] = (bf16_t)f0.x; v[1] = (bf16_t)f0.y; v[2] = (bf16_t)f0.z; v[3] = (bf16_t)f0.w;
    v[4] = (bf16_t)f1.x; v[5] = (bf16_t)f1.y; v[6] = (bf16_t)f1.z; v[7] = (bf16_t)f1.w;
    return v;
}

// ---------------------------------------------------------------------------
// prep: weight transposes. W1t[128][160] bf16 (k-pad), W2t[64][128] bf16,
// Wxt[192][64] bf16, Wht[192][64] bf16.
// ---------------------------------------------------------------------------
__global__ __launch_bounds__(256) void prep_kernel(
    const float* __restrict__ Wm1, const float* __restrict__ Wm2,
    const float* __restrict__ Wx,  const float* __restrict__ Wh,
    bf16_t* __restrict__ W1t, bf16_t* __restrict__ W2t,
    bf16_t* __restrict__ Wxt, bf16_t* __restrict__ Wht)
{
    int u = blockIdx.x * 256 + threadIdx.x;
    if (u < 20480) {
        int n = u / 160, k = u - n * 160;
        W1t[u] = (k < 136) ? (bf16_t)Wm1[k * 128 + n] : (bf16_t)0.f;
        return;
    }
    u -= 20480;
    if (u < 8192) {
        int n = u / 128, k = u - n * 128;
        W2t[u] = (bf16_t)Wm2[k * 64 + n];
        return;
    }
    u -= 8192;
    if (u < 12288) {
        int n = u >> 6, k = u & 63;
        Wxt[u] = (bf16_t)Wx[k * 192 + n];
        return;
    }
    u -= 12288;
    if (u < 12288) {
        int n = u >> 6, k = u & 63;
        Wht[u] = (bf16_t)Wh[k * 192 + n];
    }
}

// ---------------------------------------------------------------------------
// CSR build: hist -> scan (3 kernels) -> scatter (permute srcs/dsts/ef)
// ---------------------------------------------------------------------------
__global__ __launch_bounds__(256) void hist_kernel(
    const int* __restrict__ edst, int* __restrict__ deg)
{
    int e = blockIdx.x * 256 + threadIdx.x;
    if (e < NE) atomicAdd(&deg[edst[e]], 1);
}

__global__ __launch_bounds__(256) void scanA_kernel(
    const int* __restrict__ deg, int* __restrict__ chunkSums)
{
    __shared__ int s[256];
    int i = blockIdx.x * 256 + threadIdx.x;
    s[threadIdx.x] = deg[i];
    __syncthreads();
    for (int st = 128; st >= 1; st >>= 1) {
        if (threadIdx.x < st) s[threadIdx.x] += s[threadIdx.x + st];
        __syncthreads();
    }
    if (threadIdx.x == 0) chunkSums[blockIdx.x] = s[0];
}

__global__ __launch_bounds__(256) void scanB_kernel(
    const int* __restrict__ chunkSums, int* __restrict__ chunkOff)
{
    __shared__ int s[256];
    int t = threadIdx.x;
    int v = (t < NCH) ? chunkSums[t] : 0;
    s[t] = v;
    __syncthreads();
    for (int st = 1; st < 256; st <<= 1) {
        int add = (t >= st) ? s[t - st] : 0;
        __syncthreads();
        s[t] += add;
        __syncthreads();
    }
    if (t < NCH) chunkOff[t] = s[t] - v;   // exclusive
}

__global__ __launch_bounds__(256) void scanC_kernel(
    const int* __restrict__ deg, const int* __restrict__ chunkOff,
    int* __restrict__ cursor)
{
    __shared__ int s[256];
    int t = threadIdx.x;
    int i = blockIdx.x * 256 + t;
    int v = deg[i];
    s[t] = v;
    __syncthreads();
    for (int st = 1; st < 256; st <<= 1) {
        int add = (t >= st) ? s[t - st] : 0;
        __syncthreads();
        s[t] += add;
        __syncthreads();
    }
    cursor[i] = chunkOff[blockIdx.x] + s[t] - v;   // exclusive
}

__global__ __launch_bounds__(256) void scatter_kernel(
    const int* __restrict__ esrc, const int* __restrict__ edst,
    const float* __restrict__ ef,
    int* __restrict__ cursor, int* __restrict__ srcs, int* __restrict__ dsts,
    float* __restrict__ efp)
{
    int e = blockIdx.x * 256 + threadIdx.x;
    if (e >= NE) return;
    int d = edst[e];
    int p = atomicAdd(&cursor[d], 1);
    srcs[p] = esrc[e];
    dsts[p] = d;
    float4 a = *(const float4*)(ef + (size_t)e * 8);
    float4 b = *(const float4*)(ef + (size_t)e * 8 + 4);
    *(float4*)(efp + (size_t)p * 8)     = a;
    *(float4*)(efp + (size_t)p * 8 + 4) = b;
}

// ---------------------------------------------------------------------------
// edge kernel v4: persistent grid-stride blocks. W1t+W2t staged in LDS once
// per block (L1/TA pipe was the R4 bottleneck: every wave re-read 56KB of
// weights through L1 -> ~1.4GB L2 traffic). W2 frags + biases hoisted to
// registers. Per-lane idx loads -> no per-tile barrier; waves pipeline
// independently across tiles. Epilogue: register-merged direct atomics
// (sorted dsts; R4 proved write volume is not the limiter).
// ---------------------------------------------------------------------------
__global__ __launch_bounds__(256) void edge_kernel(
    const float* __restrict__ h, const float* __restrict__ efp,
    const int* __restrict__ srcs, const int* __restrict__ dsts,
    const bf16_t* __restrict__ W1t, const bf16_t* __restrict__ W2t,
    const float* __restrict__ b1f, const float* __restrict__ b2f,
    float* __restrict__ agg)
{
    __shared__ __attribute__((aligned(16))) bf16_t w1s[20480];      // 40960 B
    __shared__ __attribute__((aligned(16))) bf16_t w2s[8192];       // 16384 B
    __shared__ __attribute__((aligned(16))) bf16_t hs[4][16 * 136]; // 17408 B

    const int tid = threadIdx.x;

    // cooperative W staging (coalesced 16B chunks)
    {
        const uint4* s1 = (const uint4*)W1t;
        uint4* d1 = (uint4*)w1s;
        #pragma unroll
        for (int i = 0; i < 10; i++) d1[tid + i * 256] = s1[tid + i * 256];
        const uint4* s2 = (const uint4*)W2t;
        uint4* d2 = (uint4*)w2s;
        #pragma unroll
        for (int i = 0; i < 4; i++) d2[tid + i * 256] = s2[tid + i * 256];
    }
    __syncthreads();

    const int lane = tid & 63;
    const int wv   = tid >> 6;
    const int l15  = lane & 15;
    const int quad = lane >> 4;

    // hoist W2 fragments (same for every tile): 16 x bf16x8 = 64 VGPR
    bf16x8 w2f[4][4];
    #pragma unroll
    for (int nt = 0; nt < 4; nt++) {
        const bf16_t* bp = w2s + (nt * 16 + l15) * 128 + quad * 8;
        #pragma unroll
        for (int ks = 0; ks < 4; ks++) w2f[nt][ks] = *(const bf16x8*)(bp + ks * 32);
    }
    // hoist biases
    float b1r[8], b2r[4];
    #pragma unroll
    for (int nt = 0; nt < 8; nt++) b1r[nt] = b1f[nt * 16 + l15];
    #pragma unroll
    for (int nt = 0; nt < 4; nt++) b2r[nt] = b2f[nt * 16 + l15];

    for (int tile = blockIdx.x; tile < NTILE; tile += gridDim.x) {
        const int e0  = tile * 64;
        const int row = wv * 16 + l15;

        int si = srcs[e0 + row];
        int di = dsts[e0 + row];

        // A fragments: k-space [src64|dst64|ef8|pad24]
        bf16x8 af[5];
        {
            const float* sp0 = h + (size_t)si * 64 + quad * 8;
            const float* sp1 = h + (size_t)di * 64 + quad * 8;
            af[0] = cvt8(sp0);
            af[1] = cvt8(sp0 + 32);
            af[2] = cvt8(sp1);
            af[3] = cvt8(sp1 + 32);
            if (quad == 0) {
                af[4] = cvt8(efp + (size_t)(e0 + row) * 8);
            } else {
                #pragma unroll
                for (int q = 0; q < 8; q++) af[4][q] = (bf16_t)0.f;
            }
        }

        // ---- GEMM1 (B from LDS) ----
        floatx4 acc[8];
        #pragma unroll
        for (int nt = 0; nt < 8; nt++) { acc[nt].x = 0.f; acc[nt].y = 0.f; acc[nt].z = 0.f; acc[nt].w = 0.f; }
        #pragma unroll
        for (int nt = 0; nt < 8; nt++) {
            const bf16_t* bp = w1s + (nt * 16 + l15) * 160 + quad * 8;
            #pragma unroll
            for (int ks = 0; ks < 5; ks++) {
                bf16x8 b = *(const bf16x8*)(bp + ks * 32);
                acc[nt] = mfma16(af[ks], b, acc[nt]);
            }
        }
        #pragma unroll
        for (int nt = 0; nt < 8; nt++) {
            float bb = b1r[nt];
            int col = nt * 16 + l15;
            #pragma unroll
            for (int r = 0; r < 4; r++) {
                float v = fmaxf(acc[nt][r] + bb, 0.f);
                hs[wv][(quad * 4 + r) * 136 + col] = (bf16_t)v;
            }
        }
        // same-wave LDS write->read: compiler inserts lgkmcnt wait

        // ---- GEMM2 (B from registers) ----
        bf16x8 hf[4];
        {
            const bf16_t* hp = hs[wv] + l15 * 136 + quad * 8;
            #pragma unroll
            for (int ks = 0; ks < 4; ks++) hf[ks] = *(const bf16x8*)(hp + ks * 32);
        }
        floatx4 oa[4];
        #pragma unroll
        for (int nt = 0; nt < 4; nt++) { oa[nt].x = 0.f; oa[nt].y = 0.f; oa[nt].z = 0.f; oa[nt].w = 0.f; }
        #pragma unroll
        for (int nt = 0; nt < 4; nt++) {
            #pragma unroll
            for (int ks = 0; ks < 4; ks++) oa[nt] = mfma16(hf[ks], w2f[nt][ks], oa[nt]);
        }

        // epilogue: register-merge consecutive equal dsts, then atomics.
        // lane holds rows quad*4 + {0..3}; their dsts via one dwordx4.
        int4 d4 = *(const int4*)(dsts + e0 + wv * 16 + quad * 4);
        #pragma unroll
        for (int nt = 0; nt < 4; nt++) {
            int col = nt * 16 + l15;
            float bb = b2r[nt];
            float* ap = agg + col;
            int dcur = d4.x;
            float v = oa[nt][0] + bb;
            if (d4.y == dcur) v += oa[nt][1] + bb;
            else { atomicAdd(ap + (size_t)dcur * 64, v); dcur = d4.y; v = oa[nt][1] + bb; }
            if (d4.z == dcur) v += oa[nt][2] + bb;
            else { atomicAdd(ap + (size_t)dcur * 64, v); dcur = d4.z; v = oa[nt][2] + bb; }
            if (d4.w == dcur) v += oa[nt][3] + bb;
            else { atomicAdd(ap + (size_t)dcur * 64, v); dcur = d4.w; v = oa[nt][3] + bb; }
            atomicAdd(ap + (size_t)dcur * 64, v);
        }
    }
}

// ---------------------------------------------------------------------------
// GRU v2 (MFMA): 64 nodes/block, 16/wave. acc_z/acc_r = agg@Wx + h@Wh fused;
// candidate keeps x-part and h-part separate (reset gate scales only hh).
// ---------------------------------------------------------------------------
__global__ __launch_bounds__(256) void gru_kernel(
    const float* __restrict__ agg, const float* __restrict__ h_in,
    float* __restrict__ h_out,
    const bf16_t* __restrict__ Wxt, const bf16_t* __restrict__ Wht,
    const float* __restrict__ bg)
{
    __shared__ __attribute__((aligned(16))) float shd[64 * 68];   // 17408 B
    const int tid = threadIdx.x;
    const int n0  = blockIdx.x * 64;

    for (int idx = tid; idx < 64 * 16; idx += 256) {
        int i = idx >> 4, c = (idx & 15) * 4;
        int n = n0 + i; if (n >= NN) n = NN - 1;
        *(float4*)&shd[i * 68 + c] = *(const float4*)(h_in + (size_t)n * 64 + c);
    }
    __syncthreads();

    const int lane = tid & 63;
    const int wv   = tid >> 6;
    const int l15  = lane & 15;
    const int quad = lane >> 4;
    const int rowA = wv * 16 + l15;
    int nA = n0 + rowA; if (nA >= NN) nA = NN - 1;

    bf16x8 ax[2], ah[2];
    ax[0] = cvt8(agg + (size_t)nA * 64 + quad * 8);
    ax[1] = cvt8(agg + (size_t)nA * 64 + quad * 8 + 32);
    {
        const float* hp = shd + rowA * 68 + quad * 8;
        ah[0] = cvt8(hp);
        ah[1] = cvt8(hp + 32);
    }

    floatx4 az[4], ar[4], axh[4], ahh[4];
    #pragma unroll
    for (int nt = 0; nt < 4; nt++) {
        az[nt].x=0.f; az[nt].y=0.f; az[nt].z=0.f; az[nt].w=0.f;
        ar[nt].x=0.f; ar[nt].y=0.f; ar[nt].z=0.f; ar[nt].w=0.f;
        axh[nt].x=0.f; axh[nt].y=0.f; axh[nt].z=0.f; axh[nt].w=0.f;
        ahh[nt].x=0.f; ahh[nt].y=0.f; ahh[nt].z=0.f; ahh[nt].w=0.f;
    }
    #pragma unroll
    for (int nt = 0; nt < 4; nt++) {
        const bf16_t* bx_z = Wxt + (nt * 16 + l15) * 64 + quad * 8;
        const bf16_t* bh_z = Wht + (nt * 16 + l15) * 64 + quad * 8;
        const bf16_t* bx_r = bx_z + 64 * 64;
        const bf16_t* bh_r = bh_z + 64 * 64;
        const bf16_t* bx_h = bx_z + 128 * 64;
        const bf16_t* bh_h = bh_z + 128 * 64;
        az[nt]  = mfma16(ax[0], *(const bf16x8*)bx_z,        az[nt]);
        az[nt]  = mfma16(ax[1], *(const bf16x8*)(bx_z + 32), az[nt]);
        az[nt]  = mfma16(ah[0], *(const bf16x8*)bh_z,        az[nt]);
        az[nt]  = mfma16(ah[1], *(const bf16x8*)(bh_z + 32), az[nt]);
        ar[nt]  = mfma16(ax[0], *(const bf16x8*)bx_r,        ar[nt]);
        ar[nt]  = mfma16(ax[1], *(const bf16x8*)(bx_r + 32), ar[nt]);
        ar[nt]  = mfma16(ah[0], *(const bf16x8*)bh_r,        ar[nt]);
        ar[nt]  = mfma16(ah[1], *(const bf16x8*)(bh_r + 32), ar[nt]);
        axh[nt] = mfma16(ax[0], *(const bf16x8*)bx_h,        axh[nt]);
        axh[nt] = mfma16(ax[1], *(const bf16x8*)(bx_h + 32), axh[nt]);
        ahh[nt] = mfma16(ah[0], *(const bf16x8*)bh_h,        ahh[nt]);
        ahh[nt] = mfma16(ah[1], *(const bf16x8*)(bh_h + 32), ahh[nt]);
    }

    #pragma unroll
    for (int nt = 0; nt < 4; nt++) {
        int j = nt * 16 + l15;
        float bz = bg[j], brr = bg[64 + j], bh = bg[128 + j];
        #pragma unroll
        for (int r = 0; r < 4; r++) {
            int lrow = wv * 16 + quad * 4 + r;
            int n = n0 + lrow;
            float z  = sigm_f(az[nt][r] + bz);
            float rr = sigm_f(ar[nt][r] + brr);
            float hc = tanh_f(axh[nt][r] + bh + rr * ahh[nt][r]);
            float hold = shd[lrow * 68 + j];
            float hnew = z * hold + (1.f - z) * hc;
            if (n < NN) h_out[(size_t)n * 64 + j] = hnew;
        }
    }
}

// ---------------------------------------------------------------------------
// readout: out[n] = relu(h@Wr1 + br1) @ Wr2 + br2 ; 32 nodes/block, fp32.
// k-loop pinned unroll 1 (R1: auto-unroll -> 256 VGPR spill).
// ---------------------------------------------------------------------------
__global__ __launch_bounds__(256) void readout_kernel(
    const float* __restrict__ h, const float* __restrict__ Wr1,
    const float* __restrict__ br1, const float* __restrict__ Wr2,
    const float* __restrict__ br2, float* __restrict__ out)
{
    __shared__ float shd[32][64];
    const int tid = threadIdx.x;
    const int nb0 = blockIdx.x * 32;

    for (int idx = tid; idx < 32 * 16; idx += 256) {
        int i = idx >> 4, c = (idx & 15) * 4;
        int n = nb0 + i;
        float4 hv = make_float4(0.f, 0.f, 0.f, 0.f);
        if (n < NN) hv = *(const float4*)(h + (size_t)n * 64 + c);
        *(float4*)&shd[i][c] = hv;
    }
    __syncthreads();

    const int j  = tid & 63;
    const int wv = tid >> 6;

    float c0[8], c1[8];
    #pragma unroll
    for (int ii = 0; ii < 8; ii++) { c0[ii] = 0.f; c1[ii] = 0.f; }

    #pragma unroll 1
    for (int k0 = 0; k0 < 64; k0 += 2) {
        float2 h2[8];
        #pragma unroll
        for (int ii = 0; ii < 8; ii++) h2[ii] = *(const float2*)&shd[wv * 8 + ii][k0];
        #pragma unroll
        for (int kk = 0; kk < 2; kk++) {
            int k = k0 + kk;
            float w0 = Wr1[k * 128 + j];
            float w1 = Wr1[k * 128 + 64 + j];
            #pragma unroll
            for (int ii = 0; ii < 8; ii++) {
                float hv = kk ? h2[ii].y : h2[ii].x;
                c0[ii] = fmaf(hv, w0, c0[ii]);
                c1[ii] = fmaf(hv, w1, c1[ii]);
            }
        }
    }

    float r2a = Wr2[j], r2b = Wr2[64 + j];
    float bb0 = br1[j], bb1 = br1[64 + j];
    float br2v = br2[0];
    #pragma unroll
    for (int ii = 0; ii < 8; ii++) {
        float p = fmaxf(c0[ii] + bb0, 0.f) * r2a + fmaxf(c1[ii] + bb1, 0.f) * r2b;
        #pragma unroll
        for (int m = 32; m >= 1; m >>= 1) p += __shfl_xor(p, m, 64);
        if (j == 0) {
            int n = nb0 + wv * 8 + ii;
            if (n < NN) out[n] = p + br2v;
        }
    }
}

// ---------------------------------------------------------------------------
extern "C" void kernel_launch(void* const* d_in, const int* in_sizes, int n_in,
                              void* d_out, int out_size, void* d_ws, size_t ws_size,
                              hipStream_t stream)
{
    const float* nf  = (const float*)d_in[0];
    const float* ef  = (const float*)d_in[1];
    const int* esrc  = (const int*)d_in[2];
    const int* edst  = (const int*)d_in[3];
    const float* Wm1 = (const float*)d_in[4];
    const float* bm1 = (const float*)d_in[5];
    const float* Wm2 = (const float*)d_in[6];
    const float* bm2 = (const float*)d_in[7];
    const float* Wx  = (const float*)d_in[8];
    const float* Wh  = (const float*)d_in[9];
    const float* bg  = (const float*)d_in[10];
    const float* Wr1 = (const float*)d_in[11];
    const float* br1 = (const float*)d_in[12];
    const float* Wr2 = (const float*)d_in[13];
    const float* br2 = (const float*)d_in[14];

    char* ws = (char*)d_ws;
    float*  hbuf   = (float*)(ws);                   // 12,800,000
    float*  agg    = (float*)(ws + 12800000);        // 12,800,000
    bf16_t* W1t    = (bf16_t*)(ws + 25600000);       // 40,960
    bf16_t* W2t    = (bf16_t*)(ws + 25640960);       // 16,384
    bf16_t* Wxt    = (bf16_t*)(ws + 25657344);       // 24,576
    bf16_t* Wht    = (bf16_t*)(ws + 25681920);       // 24,576
    int*    srcs   = (int*)(ws + 25706496);          // 1,600,000
    int*    dsts   = (int*)(ws + 27306496);          // 1,600,000
    float*  efp    = (float*)(ws + 28906496);        // 12,800,000
    int*    deg    = (int*)(ws + 41706496);          // 200,704
    int*    cursor = (int*)(ws + 41907200);          // 200,704
    int*    chunkS = (int*)(ws + 42107904);          // 1,024
    int*    chunkO = (int*)(ws + 42108928);          // 1,024

    prep_kernel<<<208, 256, 0, stream>>>(Wm1, Wm2, Wx, Wh, W1t, W2t, Wxt, Wht);

    // CSR build (per launch; same work every call)
    hipMemsetAsync(deg, 0, NPAD * 4, stream);
    hist_kernel<<<(NE + 255) / 256, 256, 0, stream>>>(edst, deg);
    scanA_kernel<<<NCH, 256, 0, stream>>>(deg, chunkS);
    scanB_kernel<<<1, 256, 0, stream>>>(chunkS, chunkO);
    scanC_kernel<<<NCH, 256, 0, stream>>>(deg, chunkO, cursor);
    scatter_kernel<<<(NE + 255) / 256, 256, 0, stream>>>(esrc, edst, ef, cursor,
                                                         srcs, dsts, efp);

    for (int t = 0; t < 2; t++) {
        const float* h_in = (t == 0) ? nf : hbuf;
        hipMemsetAsync(agg, 0, (size_t)NN * 64 * 4, stream);
        edge_kernel<<<2048, 256, 0, stream>>>(h_in, efp, srcs, dsts, W1t, W2t,
                                              bm1, bm2, agg);
        gru_kernel<<<(NN + 63) / 64, 256, 0, stream>>>(agg, h_in, hbuf, Wxt, Wht, bg);
    }
    readout_kernel<<<(NN + 31) / 32, 256, 0, stream>>>(hbuf, Wr1, br1, Wr2, br2,
                                                       (float*)d_out);
}